// Round 11
// baseline (323.631 us; speedup 1.0000x reference)
//
#include <hip/hip_runtime.h>

typedef unsigned short u16;
typedef u16 u16x4 __attribute__((ext_vector_type(4)));
typedef u16 u16x8 __attribute__((ext_vector_type(8)));
typedef __bf16 bf16x8 __attribute__((ext_vector_type(8)));
typedef float f32x4 __attribute__((ext_vector_type(4)));

__device__ __forceinline__ float b2f(u16 u) {
    union { unsigned int i; float f; } v; v.i = ((unsigned int)u) << 16; return v.f;
}
__device__ __forceinline__ u16 f2b(float f) {
    union { float f; unsigned int i; } v; v.f = f;
    unsigned int r = v.i + 0x7fffu + ((v.i >> 16) & 1u);
    return (u16)(r >> 16);
}
__device__ __forceinline__ void gload_lds16(const u16* g, u16* l) {
    __builtin_amdgcn_global_load_lds(
        (const __attribute__((address_space(1))) void*)g,
        (__attribute__((address_space(3))) void*)l, 16, 0, 0);
}
__device__ __forceinline__ bf16x8 ones_frag() {
    union { u16x8 u; bf16x8 b; } v;
    #pragma unroll
    for (int i = 0; i < 8; ++i) v.u[i] = 0x3F80;
    return v.b;
}

// ---------------------------------------------------------------------------
// Fused launch A: blocks 0..2303 pack weights; 2304..3087 per-position LN
// stats for x (xmu,xrs) and y (rs, mu*rs).
// ---------------------------------------------------------------------------
__global__ __launch_bounds__(256) void pack_stats_kernel(
    const float* __restrict__ wq1, const float* __restrict__ wq2,
    const float* __restrict__ wkv, const float* __restrict__ wproj,
    u16* __restrict__ wcat, u16* __restrict__ wq2b, u16* __restrict__ wpb,
    u16* __restrict__ at_a,
    const float* __restrict__ x, const float* __restrict__ y,
    float* __restrict__ xmu, float* __restrict__ xrs,
    float* __restrict__ rsb, float* __restrict__ mrsb) {
    __shared__ float red[16][64];
    __shared__ float red2[16][64];
    const int bxg = blockIdx.x;
    const int t = threadIdx.x;
    if (bxg < 2304) {
        const int e = bxg * 256 + t;
        const float scale = 0.125f;
        wcat[e]           = f2b(wq1[e] * scale);
        wcat[589824 + e]  = f2b(wkv[e] * scale);
        wcat[1179648 + e] = f2b(wkv[589824 + e]);
        wq2b[e]           = f2b(wq2[e]);
        wpb[e]            = f2b(wproj[e]);
        if (e < 92160) {   // zero at_a pad rows 49..63 per batch
            int bb = e / 11520, rem = e - bb * 11520;
            at_a[(size_t)bb * 49152 + 37632 + rem] = 0;
        }
        return;
    }
    const int bx0 = bxg - 2304;
    const int isY = bx0 >= 392;
    const int bx = isY ? bx0 - 392 : bx0;
    const int b = bx / 49, tile = bx - b * 49;
    const int pos0 = tile * 64;
    const int pq = t & 15, q = t >> 4;
    const float* src = (isY ? y : x) + (size_t)b * 2408448 + pos0;
    f32x4 s = {0.f, 0.f, 0.f, 0.f}, s2 = {0.f, 0.f, 0.f, 0.f};
    #pragma unroll 8
    for (int c = q; c < 768; c += 16) {
        f32x4 v = *(const f32x4*)&src[(size_t)c * 3136 + pq * 4];
        s += v; s2 += v * v;
    }
    *(f32x4*)&red[q][pq * 4] = s;
    *(f32x4*)&red2[q][pq * 4] = s2;
    __syncthreads();
    if (t < 64) {
        float ss = 0.f, qq = 0.f;
        #pragma unroll
        for (int r = 0; r < 16; ++r) { ss += red[r][t]; qq += red2[r][t]; }
        float mu = ss * (1.0f / 768.0f);
        float var = qq * (1.0f / 768.0f) - mu * mu;
        float rv = rsqrtf(var + 1e-5f);
        const size_t o = (size_t)b * 3136 + pos0 + t;
        if (isY) { rsb[o] = rv; mrsb[o] = mu * rv; }
        else     { xmu[o] = mu; xrs[o] = rv; }
    }
}

// ---------------------------------------------------------------------------
// Fused launch B: blocks 0..783 = xnorm (LN+transpose x -> xn bf16);
// blocks 784..1455 = y_pool (pooled LN(y) -> at_a bf16).
// ---------------------------------------------------------------------------
__global__ __launch_bounds__(256) void norm_pool_kernel(
    const float* __restrict__ x, const float* __restrict__ lw1,
    const float* __restrict__ lb1, const float* __restrict__ xmu,
    const float* __restrict__ xrs, u16* __restrict__ xn,
    const float* __restrict__ y, const float* __restrict__ lw2,
    const float* __restrict__ lb2, const float* __restrict__ rsb,
    const float* __restrict__ mrsb, u16* __restrict__ at_a) {
    __shared__ u16 tl[128][68];
    const int bxg = blockIdx.x;
    const int t = threadIdx.x;
    if (bxg < 784) {
        const int half = bxg / 392;
        const int bx = bxg - half * 392;
        const int b = bx / 49, tile = bx - b * 49;
        const int pos0 = tile * 64;
        const int pq = t & 15, q = t >> 4;
        const int p = t >> 2, sub = t & 3;
        const float* xb = x + (size_t)b * 2408448 + pos0;
        const float mu = xmu[(size_t)b * 3136 + pos0 + p];
        const float rs = xrs[(size_t)b * 3136 + pos0 + p];
        const size_t orow = ((size_t)(b * 3136 + pos0 + p)) * 768;
        for (int ci = 0; ci < 3; ++ci) {
            const int c0 = half * 384 + ci * 128;
            #pragma unroll
            for (int s8 = 0; s8 < 8; ++s8) {
                const int cr = s8 * 16 + q;
                f32x4 v = *(const f32x4*)&xb[(size_t)(c0 + cr) * 3136 + pq * 4];
                u16x4 pk;
                pk[0] = f2b(v[0]); pk[1] = f2b(v[1]); pk[2] = f2b(v[2]); pk[3] = f2b(v[3]);
                *(u16x4*)&tl[cr][pq * 4] = pk;
            }
            __syncthreads();
            #pragma unroll
            for (int k = 0; k < 4; ++k) {
                const int cb = k * 32 + sub * 8;
                f32x4 w0 = *(const f32x4*)&lw1[c0 + cb];
                f32x4 w1 = *(const f32x4*)&lw1[c0 + cb + 4];
                f32x4 b0 = *(const f32x4*)&lb1[c0 + cb];
                f32x4 b1 = *(const f32x4*)&lb1[c0 + cb + 4];
                u16x8 o;
                #pragma unroll
                for (int j = 0; j < 4; ++j) {
                    float v = b2f(tl[cb + j][p]);
                    o[j] = f2b((v - mu) * rs * w0[j] + b0[j]);
                }
                #pragma unroll
                for (int j = 0; j < 4; ++j) {
                    float v = b2f(tl[cb + 4 + j][p]);
                    o[4 + j] = f2b((v - mu) * rs * w1[j] + b1[j]);
                }
                *(u16x8*)&xn[orow + c0 + cb] = o;
            }
            __syncthreads();
        }
        return;
    }
    // ---- y_pool half ----
    const int j = bxg - 784;
    const int cgrp = j % 12;
    const int bpi = j / 12;
    const int b = bpi / 7, pi = bpi - b * 7;
    const int lane = t & 63, w = t >> 6;
    const int pbase = b * 3136 + pi * 448;
    const int p0 = (lane >> 3) * 56 + (lane & 7);
    float rsv[7], s3f[7];
    #pragma unroll
    for (int it = 0; it < 7; ++it) {
        rsv[it] = rsb[pbase + p0 + it * 8];
        float m = mrsb[pbase + p0 + it * 8];
        #pragma unroll
        for (int msk = 1; msk < 64; msk <<= 1) m += __shfl_xor(m, msk, 64);
        s3f[it] = m;
    }
    const float* yb = y + (size_t)b * 2408448 + pi * 448 + p0;
    u16* yo = at_a + ((size_t)b * 64 + pi * 7) * 768;
    for (int ci = 0; ci < 16; ++ci) {
        const int c = cgrp * 64 + w * 16 + ci;
        const float* yc = yb + (size_t)c * 3136;
        float v[7];
        #pragma unroll
        for (int it = 0; it < 7; ++it) v[it] = yc[it * 8] * rsv[it];
        #pragma unroll
        for (int it = 0; it < 7; ++it) {
            float s = v[it];
            #pragma unroll
            for (int msk = 1; msk < 64; msk <<= 1) s += __shfl_xor(s, msk, 64);
            v[it] = s;
        }
        if (lane == 0) {
            const float wv = lw2[c], bv = lb2[c];
            #pragma unroll
            for (int it = 0; it < 7; ++it)
                yo[(size_t)it * 768 + c] = f2b(wv * (v[it] - s3f[it]) * (1.0f / 64.0f) + bv);
        }
    }
}

// ---------------------------------------------------------------------------
// 128x128 4-wave m97-structure GEMM body (proven: 114 us qkv, ~772 TF).
// Two-sided LDS slot swizzle; caller supplies (rt, ct).
// MODE 0 (qkv): cols <1536 -> qk[n][1536]; cols >=1536 -> vT[(b*768+c)][n].
// MODE 1 (proj): f32 +bias, transposed (b,o,n). MODE 2: plain bf16 [M][768].
// ---------------------------------------------------------------------------
template<int MODE>
__device__ __forceinline__ void gemm_body(
    int rt, int ct, const u16* __restrict__ A, const u16* __restrict__ B,
    u16* __restrict__ qk, u16* __restrict__ vT,
    float* __restrict__ Cf, const float* __restrict__ bias,
    u16* As, u16* Bs) {
    const int t = threadIdx.x;
    const int lane = t & 63;
    const int w = t >> 6;
    const int wr = w >> 1, wc = w & 1;
    const int l15 = lane & 15, l4 = lane >> 4;

    const u16* Ab = A + (size_t)rt * 128 * 768;
    const u16* Bb = B + (size_t)ct * 128 * 768;
    const int grh = lane >> 3;
    const int gsl = (lane & 7) ^ grh;

    f32x4 acc[4][4];
    #pragma unroll
    for (int mi = 0; mi < 4; ++mi)
        #pragma unroll
        for (int ni = 0; ni < 4; ++ni)
            acc[mi][ni] = (f32x4){0.f, 0.f, 0.f, 0.f};

    for (int kt = 0; kt < 12; ++kt) {
        if (kt) __syncthreads();
        #pragma unroll
        for (int i = 0; i < 4; ++i) {
            const int chunk = w * 4 + i;
            const int row = chunk * 8 + grh;
            gload_lds16(Ab + (size_t)row * 768 + kt * 64 + gsl * 8, &As[chunk * 512]);
            gload_lds16(Bb + (size_t)row * 768 + kt * 64 + gsl * 8, &Bs[chunk * 512]);
        }
        __syncthreads();
        #pragma unroll
        for (int ks = 0; ks < 2; ++ks) {
            bf16x8 af[4], bfv[4];
            #pragma unroll
            for (int mi = 0; mi < 4; ++mi) {
                const int row = wr * 64 + mi * 16 + l15;
                af[mi] = *(const bf16x8*)&As[row * 64 + (((ks * 4 + l4) ^ (row & 7)) * 8)];
            }
            #pragma unroll
            for (int ni = 0; ni < 4; ++ni) {
                const int row = wc * 64 + ni * 16 + l15;
                bfv[ni] = *(const bf16x8*)&Bs[row * 64 + (((ks * 4 + l4) ^ (row & 7)) * 8)];
            }
            #pragma unroll
            for (int mi = 0; mi < 4; ++mi)
                #pragma unroll
                for (int ni = 0; ni < 4; ++ni)
                    acc[mi][ni] = __builtin_amdgcn_mfma_f32_16x16x32_bf16(
                        af[mi], bfv[ni], acc[mi][ni], 0, 0, 0);
        }
    }

    if constexpr (MODE == 0) {
        #pragma unroll
        for (int mi = 0; mi < 4; ++mi)
            #pragma unroll
            for (int ni = 0; ni < 4; ++ni) {
                const int row0 = rt * 128 + wr * 64 + mi * 16 + l4 * 4;
                const int col = ct * 128 + wc * 64 + ni * 16 + l15;
                if (col < 1536) {
                    #pragma unroll
                    for (int rr = 0; rr < 4; ++rr)
                        qk[(size_t)(row0 + rr) * 1536 + col] = f2b(acc[mi][ni][rr]);
                } else {
                    const int c = col - 1536;
                    const int bb = row0 / 3136;
                    const int nn2 = row0 - bb * 3136;
                    u16x4 pk;
                    #pragma unroll
                    for (int rr = 0; rr < 4; ++rr) pk[rr] = f2b(acc[mi][ni][rr]);
                    *(u16x4*)&vT[((size_t)(bb * 768 + c)) * 3136 + nn2] = pk;
                }
            }
    } else if constexpr (MODE == 1) {
        #pragma unroll
        for (int ni = 0; ni < 4; ++ni) {
            const int col = ct * 128 + wc * 64 + ni * 16 + l15;
            const float bv = bias[col];
            #pragma unroll
            for (int mi = 0; mi < 4; ++mi) {
                const int grow = rt * 128 + wr * 64 + mi * 16 + l4 * 4;
                const int bb = grow / 3136;
                const int nn2 = grow - bb * 3136;
                f32x4 vv = acc[mi][ni];
                vv[0] += bv; vv[1] += bv; vv[2] += bv; vv[3] += bv;
                *(f32x4*)(Cf + (size_t)bb * 2408448 + (size_t)col * 3136 + nn2) = vv;
            }
        }
    } else {
        #pragma unroll
        for (int mi = 0; mi < 4; ++mi)
            #pragma unroll
            for (int ni = 0; ni < 4; ++ni) {
                const int row0 = rt * 128 + wr * 64 + mi * 16 + l4 * 4;
                const int col = ct * 128 + wc * 64 + ni * 16 + l15;
                #pragma unroll
                for (int rr = 0; rr < 4; ++rr)
                    qk[(size_t)(row0 + rr) * 768 + col] = f2b(acc[mi][ni][rr]);
            }
    }
}

// Bijective XCD swizzle + GROUP_RT=4 tile order. Requires NRT % 4 == 0.
__device__ __forceinline__ void map_tile(int orig, int nwg, int NCT,
                                         int& rt, int& ct) {
    const int xcd = orig & 7;
    const int qd = nwg >> 3, r = nwg & 7;
    const int wg = (xcd < r ? xcd * (qd + 1) : r * (qd + 1) + (xcd - r) * qd) + (orig >> 3);
    const int grp = NCT * 4;
    const int rtg = wg / grp, rem = wg % grp;
    ct = rem >> 2;
    rt = rtg * 4 + (rem & 3);
}

// Fused launch C: blocks 0..3527 = qkv GEMM; 3528..3551 = agent-token GEMM.
__global__ __launch_bounds__(256) void gemm_qkv_at_kernel(
    const u16* __restrict__ xn, const u16* __restrict__ wcat,
    u16* __restrict__ qk, u16* __restrict__ vT,
    const u16* __restrict__ at_a, const u16* __restrict__ wq2b,
    u16* __restrict__ at_bf) {
    __shared__ u16 As[128 * 64];
    __shared__ u16 Bs[128 * 64];
    const int bx = blockIdx.x;
    if (bx < 3528) {
        int rt, ct;
        map_tile(bx, 3528, 18, rt, ct);
        gemm_body<0>(rt, ct, xn, wcat, qk, vT, nullptr, nullptr, As, Bs);
    } else {
        const int wg = bx - 3528;            // 24 blocks: NRT=4, NCT=6
        gemm_body<2>(wg / 6, wg % 6, at_a, wq2b, at_bf, nullptr, nullptr, nullptr, As, Bs);
    }
}

__global__ __launch_bounds__(256) void gemm_proj_kernel(
    const u16* __restrict__ attn_out, const u16* __restrict__ wpb,
    float* __restrict__ out, const float* __restrict__ bproj) {
    __shared__ u16 As[128 * 64];
    __shared__ u16 Bs[128 * 64];
    int rt, ct;
    map_tile(blockIdx.x, 1176, 6, rt, ct);
    gemm_body<1>(rt, ct, attn_out, wpb, nullptr, nullptr, out, bproj, As, Bs);
}

// ---------------------------------------------------------------------------
// Agent-side attention (MFMA), n-split x7 partials per (b,h).
// K and V fragments read DIRECTLY from global (qk/vT are L2/L3-resident —
// LDS staging was a pure round-trip). Only P stays in LDS. 2 barriers/tile.
// ---------------------------------------------------------------------------
__global__ __launch_bounds__(256) void agent_attn_kernel(
    const u16* __restrict__ at_bf, const u16* __restrict__ qk,
    const u16* __restrict__ vT, float* __restrict__ ps,
    float* __restrict__ pav_t) {
    __shared__ u16 p_lds[64 * 64];       // [a][n'], pair-swizzled (8 KB)
    const int ns = blockIdx.x;
    const int bh = blockIdx.y;
    const int b = bh / 12, h = bh - b * 12;
    const int t = threadIdx.x, lane = t & 63, w = t >> 6;
    const int l15 = lane & 15, l4 = lane >> 4;

    bf16x8 atf[2];
    #pragma unroll
    for (int ks = 0; ks < 2; ++ks)
        atf[ks] = *(const bf16x8*)&at_bf[((size_t)b * 64 + 16 * w + l15) * 768 + h * 64 + ks * 32 + l4 * 8];
    const bf16x8 onef = ones_frag();

    const u16* kbase = qk + 768 + h * 64;             // + (b*3136+n)*1536
    const u16* vbase = vT + (size_t)(bh * 64) * 3136; // + d*3136 + n

    f32x4 acc_o[4], acc_den[4];
    #pragma unroll
    for (int mi = 0; mi < 4; ++mi) {
        acc_o[mi] = (f32x4){0.f, 0.f, 0.f, 0.f};
        acc_den[mi] = (f32x4){0.f, 0.f, 0.f, 0.f};
    }

    for (int tile = 0; tile < 7; ++tile) {
        const int n0 = ns * 448 + tile * 64;
        if (tile) __syncthreads();           // prev PV done before p_lds overwrite
        // S^T = K . at^T  (K-frags direct from L2)
        f32x4 acc_s[4];
        #pragma unroll
        for (int mi = 0; mi < 4; ++mi) acc_s[mi] = (f32x4){0.f, 0.f, 0.f, 0.f};
        #pragma unroll
        for (int ks = 0; ks < 2; ++ks)
            #pragma unroll
            for (int mi = 0; mi < 4; ++mi) {
                const int row = 16 * mi + l15;
                bf16x8 kf = *(const bf16x8*)&kbase[(size_t)(b * 3136 + n0 + row) * 1536 + ks * 32 + l4 * 8];
                acc_s[mi] = __builtin_amdgcn_mfma_f32_16x16x32_bf16(kf, atf[ks], acc_s[mi], 0, 0, 0);
            }
        // exp + pack -> P_lds[a][n']
        const int a_w = 16 * w + l15;
        #pragma unroll
        for (int mi = 0; mi < 4; ++mi) {
            u16x4 pk;
            #pragma unroll
            for (int rr = 0; rr < 4; ++rr) pk[rr] = f2b(__expf(acc_s[mi][rr]));
            const int pp = (2 * mi + (l4 >> 1)) ^ (a_w & 7);
            *(u16x4*)((char*)p_lds + a_w * 128 + pp * 16 + (l4 & 1) * 8) = pk;
        }
        __syncthreads();                     // P visible
        // PV + den (V-frags direct from L2)
        #pragma unroll
        for (int ks = 0; ks < 2; ++ks) {
            const int d = 16 * w + l15;
            bf16x8 vf = *(const bf16x8*)&vbase[(size_t)d * 3136 + n0 + ks * 32 + l4 * 8];
            #pragma unroll
            for (int mi = 0; mi < 4; ++mi) {
                const int a = 16 * mi + l15;
                bf16x8 pf = *(const bf16x8*)((char*)p_lds + a * 128 + (((ks * 4 + l4) ^ (a & 7)) * 16));
                acc_o[mi] = __builtin_amdgcn_mfma_f32_16x16x32_bf16(pf, vf, acc_o[mi], 0, 0, 0);
                acc_den[mi] = __builtin_amdgcn_mfma_f32_16x16x32_bf16(onef, pf, acc_den[mi], 0, 0, 0);
            }
        }
    }
    const size_t pbase = (size_t)bh * 7 + ns;
    if (w == 0 && lane < 16) {
        #pragma unroll
        for (int mi = 0; mi < 4; ++mi)
            ps[pbase * 64 + 16 * mi + lane] = acc_den[mi][0];
    }
    #pragma unroll
    for (int mi = 0; mi < 4; ++mi)
        *(f32x4*)&pav_t[(pbase * 64 + 16 * w + l15) * 64 + 16 * mi + l4 * 4] = acc_o[mi];
}

// ---------------------------------------------------------------------------
// Q-side attention with INLINED combine; q fragments direct from L2
// (qk is L3-resident). LDS: p_lds + av_lds only. 2 barriers/iter.
// ---------------------------------------------------------------------------
__global__ __launch_bounds__(256) void q_attn_kernel(
    const u16* __restrict__ at_bf, const u16* __restrict__ qk,
    const float* __restrict__ ps, const float* __restrict__ pav_t,
    u16* __restrict__ attn_out) {
    __shared__ u16 p_lds[64 * 64];    // [n][a], pair-swizzled
    __shared__ u16 av_lds[64 * 64];   // [d][a]
    __shared__ float sinv[64];
    const int grp = blockIdx.x;
    const int bh = blockIdx.y;
    const int b = bh / 12, h = bh - b * 12;
    const int t = threadIdx.x, lane = t & 63, w = t >> 6;
    const int l15 = lane & 15, l4 = lane >> 4;

    // ---- inline combine: av_lds[d][a] = (sum_ns pav_t) * sinv[a] ----
    if (t < 64) {
        float s = 0.f;
        #pragma unroll
        for (int ns = 0; ns < 7; ++ns) s += ps[((size_t)bh * 7 + ns) * 64 + t];
        sinv[t] = 1.0f / s;
    }
    __syncthreads();
    {
        const int d = t >> 2, aseg = t & 3;
        f32x4 acc[4];
        #pragma unroll
        for (int g = 0; g < 4; ++g) acc[g] = (f32x4){0.f, 0.f, 0.f, 0.f};
        #pragma unroll
        for (int ns = 0; ns < 7; ++ns) {
            const float* src = pav_t + (((size_t)bh * 7 + ns) * 64 + d) * 64 + aseg * 16;
            #pragma unroll
            for (int g = 0; g < 4; ++g) acc[g] += *(const f32x4*)&src[g * 4];
        }
        u16x8 o0, o1;
        #pragma unroll
        for (int g = 0; g < 4; ++g)
            #pragma unroll
            for (int jj = 0; jj < 4; ++jj) {
                const u16 v = f2b(acc[g][jj] * sinv[aseg * 16 + g * 4 + jj]);
                if (g < 2) o0[g * 4 + jj] = v; else o1[(g - 2) * 4 + jj] = v;
            }
        *(u16x8*)&av_lds[d * 64 + aseg * 16] = o0;
        *(u16x8*)&av_lds[d * 64 + aseg * 16 + 8] = o1;
    }
    __syncthreads();

    bf16x8 atf[4][2], avf[4][2];
    #pragma unroll
    for (int mi = 0; mi < 4; ++mi)
        #pragma unroll
        for (int ks = 0; ks < 2; ++ks) {
            atf[mi][ks] = *(const bf16x8*)&at_bf[((size_t)b * 64 + 16 * mi + l15) * 768 + h * 64 + ks * 32 + l4 * 8];
            avf[mi][ks] = *(const bf16x8*)&av_lds[(16 * mi + l15) * 64 + ks * 32 + l4 * 8];
        }
    const bf16x8 onef = ones_frag();
    const u16* qbase = qk + h * 64;   // + (b*3136+n)*1536

    const int nn = 16 * w + l15;
    for (int i = 0; i < 7; ++i) {
        const int nt = grp * 7 + i;
        const int n0 = nt * 64;
        if (i) __syncthreads();              // prev PV done before p_lds overwrite
        // L^T = at . q^T  (q-frags direct from L2)
        f32x4 acc_l[4];
        #pragma unroll
        for (int mi = 0; mi < 4; ++mi) acc_l[mi] = (f32x4){0.f, 0.f, 0.f, 0.f};
        #pragma unroll
        for (int ks = 0; ks < 2; ++ks) {
            bf16x8 qf = *(const bf16x8*)&qbase[(size_t)(b * 3136 + n0 + nn) * 1536 + ks * 32 + l4 * 8];
            #pragma unroll
            for (int mi = 0; mi < 4; ++mi)
                acc_l[mi] = __builtin_amdgcn_mfma_f32_16x16x32_bf16(atf[mi][ks], qf, acc_l[mi], 0, 0, 0);
        }
        #pragma unroll
        for (int mi = 0; mi < 4; ++mi) {
            u16x4 pk;
            #pragma unroll
            for (int rr = 0; rr < 4; ++rr) {
                const int a = 16 * mi + l4 * 4 + rr;
                pk[rr] = (a < 49) ? f2b(__expf(acc_l[mi][rr])) : (u16)0;
            }
            const int pp = (2 * mi + (l4 >> 1)) ^ (nn & 7);
            *(u16x4*)((char*)p_lds + nn * 128 + pp * 16 + (l4 & 1) * 8) = pk;
        }
        __syncthreads();                     // P visible
        f32x4 acc_o[4], den;
        #pragma unroll
        for (int mi = 0; mi < 4; ++mi) acc_o[mi] = (f32x4){0.f, 0.f, 0.f, 0.f};
        den = (f32x4){0.f, 0.f, 0.f, 0.f};
        #pragma unroll
        for (int ks = 0; ks < 2; ++ks) {
            bf16x8 pf = *(const bf16x8*)((char*)p_lds + nn * 128 + (((ks * 4 + l4) ^ (nn & 7)) * 16));
            den = __builtin_amdgcn_mfma_f32_16x16x32_bf16(onef, pf, den, 0, 0, 0);
            #pragma unroll
            for (int mi = 0; mi < 4; ++mi)
                acc_o[mi] = __builtin_amdgcn_mfma_f32_16x16x32_bf16(avf[mi][ks], pf, acc_o[mi], 0, 0, 0);
        }
        const float rinv = 1.0f / den[0];
        const size_t obase = ((size_t)(b * 3136 + n0 + nn)) * 768 + h * 64;
        #pragma unroll
        for (int mi = 0; mi < 4; ++mi) {
            u16x4 ov;
            #pragma unroll
            for (int rr = 0; rr < 4; ++rr) ov[rr] = f2b(acc_o[mi][rr] * rinv);
            *(u16x4*)&attn_out[obase + 16 * mi + l4 * 4] = ov;
        }
    }
}

// ---------------------------------------------------------------------------
extern "C" void kernel_launch(void* const* d_in, const int* in_sizes, int n_in,
                              void* d_out, int out_size, void* d_ws, size_t ws_size,
                              hipStream_t stream) {
    (void)in_sizes; (void)n_in; (void)out_size; (void)ws_size;
    const float* x     = (const float*)d_in[0];
    const float* y     = (const float*)d_in[1];
    const float* ln1w  = (const float*)d_in[2];
    const float* ln1b  = (const float*)d_in[3];
    const float* ln2w  = (const float*)d_in[4];
    const float* ln2b  = (const float*)d_in[5];
    const float* wq1   = (const float*)d_in[6];
    const float* wq2   = (const float*)d_in[7];
    const float* wkv   = (const float*)d_in[8];
    const float* wproj = (const float*)d_in[9];
    const float* bproj = (const float*)d_in[10];
    float* out = (float*)d_out;

    char* ws = (char*)d_ws;
    // Regions. Aliasing plan:
    //   xn region: xn (written B, read C) -> pav_t (written D, read E)
    //   vT region: vT (written C, read D) -> attn_out (written E, read F)
    u16*   xn     = (u16*)(ws);                    // 38,535,168
    u16*   qk     = (u16*)(ws + 38535168);         // 77,070,336 ([n][1536])
    u16*   vT     = (u16*)(ws + 115605504);        // 38,535,168 ([b*768+c][n])
    u16*   wcat   = (u16*)(ws + 154140672);        // 3,538,944
    u16*   wq2b   = (u16*)(ws + 157679616);        // 1,179,648
    u16*   wpb    = (u16*)(ws + 158859264);        // 1,179,648
    u16*   at_a   = (u16*)(ws + 160038912);        // 786,432
    u16*   at_bf  = (u16*)(ws + 160825344);        // 786,432
    float* ps     = (float*)(ws + 161611776);      // 172,032
    float* rsb    = (float*)(ws + 161783808);      // 100,352
    float* mrsb   = (float*)(ws + 161884160);      // 100,352
    float* xmu    = (float*)(ws + 161984512);      // 100,352
    float* xrs    = (float*)(ws + 162084864);      // 100,352 (end 162,185,216)
    float* pav_t  = (float*)(ws);                  // in xn region
    u16*   attn_out = vT;                          // in vT region

    pack_stats_kernel<<<dim3(3088), dim3(256), 0, stream>>>(
        wq1, wq2, wkv, wproj, wcat, wq2b, wpb, at_a, x, y, xmu, xrs, rsb, mrsb);
    norm_pool_kernel<<<dim3(1456), dim3(256), 0, stream>>>(
        x, ln1w, ln1b, xmu, xrs, xn, y, ln2w, ln2b, rsb, mrsb, at_a);
    gemm_qkv_at_kernel<<<dim3(3552), dim3(256), 0, stream>>>(
        xn, wcat, qk, vT, at_a, wq2b, at_bf);
    agent_attn_kernel<<<dim3(7, 96), dim3(256), 0, stream>>>(at_bf, qk, vT, ps, pav_t);
    q_attn_kernel<<<dim3(7, 96), dim3(256), 0, stream>>>(at_bf, qk, ps, pav_t, attn_out);
    gemm_proj_kernel<<<dim3(1176), dim3(256), 0, stream>>>(attn_out, wpb, out, bproj);
}

// Round 12
// 304.298 us; speedup vs baseline: 1.0635x; 1.0635x over previous
//
#include <hip/hip_runtime.h>

typedef unsigned short u16;
typedef u16 u16x4 __attribute__((ext_vector_type(4)));
typedef u16 u16x8 __attribute__((ext_vector_type(8)));
typedef __bf16 bf16x8 __attribute__((ext_vector_type(8)));
typedef float f32x4 __attribute__((ext_vector_type(4)));

__device__ __forceinline__ float b2f(u16 u) {
    union { unsigned int i; float f; } v; v.i = ((unsigned int)u) << 16; return v.f;
}
__device__ __forceinline__ u16 f2b(float f) {
    union { float f; unsigned int i; } v; v.f = f;
    unsigned int r = v.i + 0x7fffu + ((v.i >> 16) & 1u);
    return (u16)(r >> 16);
}
__device__ __forceinline__ void gload_lds16(const u16* g, u16* l) {
    __builtin_amdgcn_global_load_lds(
        (const __attribute__((address_space(1))) void*)g,
        (__attribute__((address_space(3))) void*)l, 16, 0, 0);
}
__device__ __forceinline__ bf16x8 ones_frag() {
    union { u16x8 u; bf16x8 b; } v;
    #pragma unroll
    for (int i = 0; i < 8; ++i) v.u[i] = 0x3F80;
    return v.b;
}
#define LGKM_BARRIER do { \
    asm volatile("s_waitcnt lgkmcnt(0)" ::: "memory"); \
    __builtin_amdgcn_s_barrier(); \
    __builtin_amdgcn_sched_barrier(0); } while (0)

// ---------------------------------------------------------------------------
// Fused launch A: blocks 0..2303 pack weights; 2304..3087 per-position LN
// stats for x (xmu,xrs) and y (rs, mu*rs).
// ---------------------------------------------------------------------------
__global__ __launch_bounds__(256) void pack_stats_kernel(
    const float* __restrict__ wq1, const float* __restrict__ wq2,
    const float* __restrict__ wkv, const float* __restrict__ wproj,
    u16* __restrict__ wcat, u16* __restrict__ wq2b, u16* __restrict__ wpb,
    u16* __restrict__ at_a,
    const float* __restrict__ x, const float* __restrict__ y,
    float* __restrict__ xmu, float* __restrict__ xrs,
    float* __restrict__ rsb, float* __restrict__ mrsb) {
    __shared__ float red[16][64];
    __shared__ float red2[16][64];
    const int bxg = blockIdx.x;
    const int t = threadIdx.x;
    if (bxg < 2304) {
        const int e = bxg * 256 + t;
        const float scale = 0.125f;
        wcat[e]           = f2b(wq1[e] * scale);
        wcat[589824 + e]  = f2b(wkv[e] * scale);
        wcat[1179648 + e] = f2b(wkv[589824 + e]);
        wq2b[e]           = f2b(wq2[e]);
        wpb[e]            = f2b(wproj[e]);
        if (e < 92160) {   // zero at_a pad rows 49..63 per batch
            int bb = e / 11520, rem = e - bb * 11520;
            at_a[(size_t)bb * 49152 + 37632 + rem] = 0;
        }
        return;
    }
    const int bx0 = bxg - 2304;
    const int isY = bx0 >= 392;
    const int bx = isY ? bx0 - 392 : bx0;
    const int b = bx / 49, tile = bx - b * 49;
    const int pos0 = tile * 64;
    const int pq = t & 15, q = t >> 4;
    const float* src = (isY ? y : x) + (size_t)b * 2408448 + pos0;
    f32x4 s = {0.f, 0.f, 0.f, 0.f}, s2 = {0.f, 0.f, 0.f, 0.f};
    #pragma unroll 8
    for (int c = q; c < 768; c += 16) {
        f32x4 v = *(const f32x4*)&src[(size_t)c * 3136 + pq * 4];
        s += v; s2 += v * v;
    }
    *(f32x4*)&red[q][pq * 4] = s;
    *(f32x4*)&red2[q][pq * 4] = s2;
    __syncthreads();
    if (t < 64) {
        float ss = 0.f, qq = 0.f;
        #pragma unroll
        for (int r = 0; r < 16; ++r) { ss += red[r][t]; qq += red2[r][t]; }
        float mu = ss * (1.0f / 768.0f);
        float var = qq * (1.0f / 768.0f) - mu * mu;
        float rv = rsqrtf(var + 1e-5f);
        const size_t o = (size_t)b * 3136 + pos0 + t;
        if (isY) { rsb[o] = rv; mrsb[o] = mu * rv; }
        else     { xmu[o] = mu; xrs[o] = rv; }
    }
}

// ---------------------------------------------------------------------------
// Fused launch B: blocks 0..783 = xnorm (LN+transpose x -> xn bf16);
// blocks 784..1455 = y_pool (pooled LN(y) -> at_a bf16).
// ---------------------------------------------------------------------------
__global__ __launch_bounds__(256) void norm_pool_kernel(
    const float* __restrict__ x, const float* __restrict__ lw1,
    const float* __restrict__ lb1, const float* __restrict__ xmu,
    const float* __restrict__ xrs, u16* __restrict__ xn,
    const float* __restrict__ y, const float* __restrict__ lw2,
    const float* __restrict__ lb2, const float* __restrict__ rsb,
    const float* __restrict__ mrsb, u16* __restrict__ at_a) {
    __shared__ u16 tl[128][68];
    const int bxg = blockIdx.x;
    const int t = threadIdx.x;
    if (bxg < 784) {
        const int half = bxg / 392;
        const int bx = bxg - half * 392;
        const int b = bx / 49, tile = bx - b * 49;
        const int pos0 = tile * 64;
        const int pq = t & 15, q = t >> 4;
        const int p = t >> 2, sub = t & 3;
        const float* xb = x + (size_t)b * 2408448 + pos0;
        const float mu = xmu[(size_t)b * 3136 + pos0 + p];
        const float rs = xrs[(size_t)b * 3136 + pos0 + p];
        const size_t orow = ((size_t)(b * 3136 + pos0 + p)) * 768;
        for (int ci = 0; ci < 3; ++ci) {
            const int c0 = half * 384 + ci * 128;
            #pragma unroll
            for (int s8 = 0; s8 < 8; ++s8) {
                const int cr = s8 * 16 + q;
                f32x4 v = *(const f32x4*)&xb[(size_t)(c0 + cr) * 3136 + pq * 4];
                u16x4 pk;
                pk[0] = f2b(v[0]); pk[1] = f2b(v[1]); pk[2] = f2b(v[2]); pk[3] = f2b(v[3]);
                *(u16x4*)&tl[cr][pq * 4] = pk;
            }
            __syncthreads();
            #pragma unroll
            for (int k = 0; k < 4; ++k) {
                const int cb = k * 32 + sub * 8;
                f32x4 w0 = *(const f32x4*)&lw1[c0 + cb];
                f32x4 w1 = *(const f32x4*)&lw1[c0 + cb + 4];
                f32x4 b0 = *(const f32x4*)&lb1[c0 + cb];
                f32x4 b1 = *(const f32x4*)&lb1[c0 + cb + 4];
                u16x8 o;
                #pragma unroll
                for (int j = 0; j < 4; ++j) {
                    float v = b2f(tl[cb + j][p]);
                    o[j] = f2b((v - mu) * rs * w0[j] + b0[j]);
                }
                #pragma unroll
                for (int j = 0; j < 4; ++j) {
                    float v = b2f(tl[cb + 4 + j][p]);
                    o[4 + j] = f2b((v - mu) * rs * w1[j] + b1[j]);
                }
                *(u16x8*)&xn[orow + c0 + cb] = o;
            }
            __syncthreads();
        }
        return;
    }
    // ---- y_pool half ----
    const int j = bxg - 784;
    const int cgrp = j % 12;
    const int bpi = j / 12;
    const int b = bpi / 7, pi = bpi - b * 7;
    const int lane = t & 63, w = t >> 6;
    const int pbase = b * 3136 + pi * 448;
    const int p0 = (lane >> 3) * 56 + (lane & 7);
    float rsv[7], s3f[7];
    #pragma unroll
    for (int it = 0; it < 7; ++it) {
        rsv[it] = rsb[pbase + p0 + it * 8];
        float m = mrsb[pbase + p0 + it * 8];
        #pragma unroll
        for (int msk = 1; msk < 64; msk <<= 1) m += __shfl_xor(m, msk, 64);
        s3f[it] = m;
    }
    const float* yb = y + (size_t)b * 2408448 + pi * 448 + p0;
    u16* yo = at_a + ((size_t)b * 64 + pi * 7) * 768;
    for (int ci = 0; ci < 16; ++ci) {
        const int c = cgrp * 64 + w * 16 + ci;
        const float* yc = yb + (size_t)c * 3136;
        float v[7];
        #pragma unroll
        for (int it = 0; it < 7; ++it) v[it] = yc[it * 8] * rsv[it];
        #pragma unroll
        for (int it = 0; it < 7; ++it) {
            float s = v[it];
            #pragma unroll
            for (int msk = 1; msk < 64; msk <<= 1) s += __shfl_xor(s, msk, 64);
            v[it] = s;
        }
        if (lane == 0) {
            const float wv = lw2[c], bv = lb2[c];
            #pragma unroll
            for (int it = 0; it < 7; ++it)
                yo[(size_t)it * 768 + c] = f2b(wv * (v[it] - s3f[it]) * (1.0f / 64.0f) + bv);
        }
    }
}

// ---------------------------------------------------------------------------
// 128x128 4-wave m97-structure GEMM body (proven: 114 us qkv, ~772 TF).
// Two-sided LDS slot swizzle; caller supplies (rt, ct).
// MODE 0 (qkv): cols <1536 -> qk[n][1536]; cols >=1536 -> vT[(b*768+c)][n].
// MODE 1 (proj): f32 +bias, transposed (b,o,n). MODE 2: plain bf16 [M][768].
// ---------------------------------------------------------------------------
template<int MODE>
__device__ __forceinline__ void gemm_body(
    int rt, int ct, const u16* __restrict__ A, const u16* __restrict__ B,
    u16* __restrict__ qk, u16* __restrict__ vT,
    float* __restrict__ Cf, const float* __restrict__ bias,
    u16* As, u16* Bs) {
    const int t = threadIdx.x;
    const int lane = t & 63;
    const int w = t >> 6;
    const int wr = w >> 1, wc = w & 1;
    const int l15 = lane & 15, l4 = lane >> 4;

    const u16* Ab = A + (size_t)rt * 128 * 768;
    const u16* Bb = B + (size_t)ct * 128 * 768;
    const int grh = lane >> 3;
    const int gsl = (lane & 7) ^ grh;

    f32x4 acc[4][4];
    #pragma unroll
    for (int mi = 0; mi < 4; ++mi)
        #pragma unroll
        for (int ni = 0; ni < 4; ++ni)
            acc[mi][ni] = (f32x4){0.f, 0.f, 0.f, 0.f};

    for (int kt = 0; kt < 12; ++kt) {
        if (kt) __syncthreads();
        #pragma unroll
        for (int i = 0; i < 4; ++i) {
            const int chunk = w * 4 + i;
            const int row = chunk * 8 + grh;
            gload_lds16(Ab + (size_t)row * 768 + kt * 64 + gsl * 8, &As[chunk * 512]);
            gload_lds16(Bb + (size_t)row * 768 + kt * 64 + gsl * 8, &Bs[chunk * 512]);
        }
        __syncthreads();
        #pragma unroll
        for (int ks = 0; ks < 2; ++ks) {
            bf16x8 af[4], bfv[4];
            #pragma unroll
            for (int mi = 0; mi < 4; ++mi) {
                const int row = wr * 64 + mi * 16 + l15;
                af[mi] = *(const bf16x8*)&As[row * 64 + (((ks * 4 + l4) ^ (row & 7)) * 8)];
            }
            #pragma unroll
            for (int ni = 0; ni < 4; ++ni) {
                const int row = wc * 64 + ni * 16 + l15;
                bfv[ni] = *(const bf16x8*)&Bs[row * 64 + (((ks * 4 + l4) ^ (row & 7)) * 8)];
            }
            #pragma unroll
            for (int mi = 0; mi < 4; ++mi)
                #pragma unroll
                for (int ni = 0; ni < 4; ++ni)
                    acc[mi][ni] = __builtin_amdgcn_mfma_f32_16x16x32_bf16(
                        af[mi], bfv[ni], acc[mi][ni], 0, 0, 0);
        }
    }

    if constexpr (MODE == 0) {
        #pragma unroll
        for (int mi = 0; mi < 4; ++mi)
            #pragma unroll
            for (int ni = 0; ni < 4; ++ni) {
                const int row0 = rt * 128 + wr * 64 + mi * 16 + l4 * 4;
                const int col = ct * 128 + wc * 64 + ni * 16 + l15;
                if (col < 1536) {
                    #pragma unroll
                    for (int rr = 0; rr < 4; ++rr)
                        qk[(size_t)(row0 + rr) * 1536 + col] = f2b(acc[mi][ni][rr]);
                } else {
                    const int c = col - 1536;
                    const int bb = row0 / 3136;
                    const int nn2 = row0 - bb * 3136;
                    u16x4 pk;
                    #pragma unroll
                    for (int rr = 0; rr < 4; ++rr) pk[rr] = f2b(acc[mi][ni][rr]);
                    *(u16x4*)&vT[((size_t)(bb * 768 + c)) * 3136 + nn2] = pk;
                }
            }
    } else if constexpr (MODE == 1) {
        #pragma unroll
        for (int ni = 0; ni < 4; ++ni) {
            const int col = ct * 128 + wc * 64 + ni * 16 + l15;
            const float bv = bias[col];
            #pragma unroll
            for (int mi = 0; mi < 4; ++mi) {
                const int grow = rt * 128 + wr * 64 + mi * 16 + l4 * 4;
                const int bb = grow / 3136;
                const int nn2 = grow - bb * 3136;
                f32x4 vv = acc[mi][ni];
                vv[0] += bv; vv[1] += bv; vv[2] += bv; vv[3] += bv;
                *(f32x4*)(Cf + (size_t)bb * 2408448 + (size_t)col * 3136 + nn2) = vv;
            }
        }
    } else {
        #pragma unroll
        for (int mi = 0; mi < 4; ++mi)
            #pragma unroll
            for (int ni = 0; ni < 4; ++ni) {
                const int row0 = rt * 128 + wr * 64 + mi * 16 + l4 * 4;
                const int col = ct * 128 + wc * 64 + ni * 16 + l15;
                #pragma unroll
                for (int rr = 0; rr < 4; ++rr)
                    qk[(size_t)(row0 + rr) * 768 + col] = f2b(acc[mi][ni][rr]);
            }
    }
}

// Bijective XCD swizzle + GROUP_RT=4 tile order. Requires NRT % 4 == 0.
__device__ __forceinline__ void map_tile(int orig, int nwg, int NCT,
                                         int& rt, int& ct) {
    const int xcd = orig & 7;
    const int qd = nwg >> 3, r = nwg & 7;
    const int wg = (xcd < r ? xcd * (qd + 1) : r * (qd + 1) + (xcd - r) * qd) + (orig >> 3);
    const int grp = NCT * 4;
    const int rtg = wg / grp, rem = wg % grp;
    ct = rem >> 2;
    rt = rtg * 4 + (rem & 3);
}

// Fused launch C: blocks 0..3527 = qkv GEMM; 3528..3551 = agent-token GEMM.
__global__ __launch_bounds__(256) void gemm_qkv_at_kernel(
    const u16* __restrict__ xn, const u16* __restrict__ wcat,
    u16* __restrict__ qk, u16* __restrict__ vT,
    const u16* __restrict__ at_a, const u16* __restrict__ wq2b,
    u16* __restrict__ at_bf) {
    __shared__ u16 As[128 * 64];
    __shared__ u16 Bs[128 * 64];
    const int bx = blockIdx.x;
    if (bx < 3528) {
        int rt, ct;
        map_tile(bx, 3528, 18, rt, ct);
        gemm_body<0>(rt, ct, xn, wcat, qk, vT, nullptr, nullptr, As, Bs);
    } else {
        const int wg = bx - 3528;            // 24 blocks: NRT=4, NCT=6
        gemm_body<2>(wg / 6, wg % 6, at_a, wq2b, at_bf, nullptr, nullptr, nullptr, As, Bs);
    }
}

__global__ __launch_bounds__(256) void gemm_proj_kernel(
    const u16* __restrict__ attn_out, const u16* __restrict__ wpb,
    float* __restrict__ out, const float* __restrict__ bproj) {
    __shared__ u16 As[128 * 64];
    __shared__ u16 Bs[128 * 64];
    int rt, ct;
    map_tile(blockIdx.x, 1176, 6, rt, ct);
    gemm_body<1>(rt, ct, attn_out, wpb, nullptr, nullptr, out, bproj, As, Bs);
}

// ---------------------------------------------------------------------------
// Agent-side attention (MFMA), n-split x7 partials per (b,h). LDS-staged K/V
// (staging IS the coalescing transform — R11 direct-L2 reads regressed 20us:
// per-fragment global reads are 16-way uncoalesced gathers).
// ---------------------------------------------------------------------------
__global__ __launch_bounds__(256) void agent_attn_kernel(
    const u16* __restrict__ at_bf, const u16* __restrict__ qk,
    const u16* __restrict__ vT, float* __restrict__ ps,
    float* __restrict__ pav_t) {
    __shared__ u16 k_lds[2][64 * 64];
    __shared__ u16 vt_lds[2][64 * 64];
    __shared__ u16 p_lds[64 * 64];
    const int ns = blockIdx.x;
    const int bh = blockIdx.y;
    const int b = bh / 12, h = bh - b * 12;
    const int t = threadIdx.x, lane = t & 63, w = t >> 6;
    const int l15 = lane & 15, l4 = lane >> 4;

    bf16x8 atf[2];
    #pragma unroll
    for (int ks = 0; ks < 2; ++ks)
        atf[ks] = *(const bf16x8*)&at_bf[((size_t)b * 64 + 16 * w + l15) * 768 + h * 64 + ks * 32 + l4 * 8];
    const bf16x8 onef = ones_frag();

    f32x4 acc_o[4], acc_den[4];
    #pragma unroll
    for (int mi = 0; mi < 4; ++mi) {
        acc_o[mi] = (f32x4){0.f, 0.f, 0.f, 0.f};
        acc_den[mi] = (f32x4){0.f, 0.f, 0.f, 0.f};
    }

    auto STAGE = [&](int buf, int tile) {
        const int n0 = ns * 448 + tile * 64;
        #pragma unroll
        for (int p = 0; p < 2; ++p) {
            const int row = p * 32 + w * 8 + (lane >> 3);
            const int sc = ((lane & 7) ^ (row & 7)) * 8;
            gload_lds16(qk + ((size_t)(b * 3136 + n0 + row)) * 1536 + 768 + h * 64 + sc,
                        &k_lds[buf][(p * 32 + w * 8) * 64]);
            gload_lds16(vT + ((size_t)(bh * 64 + row)) * 3136 + n0 + sc,
                        &vt_lds[buf][(p * 32 + w * 8) * 64]);
        }
    };

    STAGE(0, 0);
    for (int tile = 0; tile < 7; ++tile) {
        const int buf = tile & 1;
        __syncthreads();
        if (tile < 6) STAGE(buf ^ 1, tile + 1);
        f32x4 acc_s[4];
        #pragma unroll
        for (int mi = 0; mi < 4; ++mi) acc_s[mi] = (f32x4){0.f, 0.f, 0.f, 0.f};
        #pragma unroll
        for (int ks = 0; ks < 2; ++ks)
            #pragma unroll
            for (int mi = 0; mi < 4; ++mi) {
                const int row = 16 * mi + l15;
                bf16x8 kf = *(const bf16x8*)&k_lds[buf][row * 64 + (((ks * 4 + l4) ^ (row & 7)) * 8)];
                acc_s[mi] = __builtin_amdgcn_mfma_f32_16x16x32_bf16(kf, atf[ks], acc_s[mi], 0, 0, 0);
            }
        const int a_w = 16 * w + l15;
        #pragma unroll
        for (int mi = 0; mi < 4; ++mi) {
            u16x4 pk;
            #pragma unroll
            for (int rr = 0; rr < 4; ++rr) pk[rr] = f2b(__expf(acc_s[mi][rr]));
            const int pp = (2 * mi + (l4 >> 1)) ^ (a_w & 7);
            *(u16x4*)((char*)p_lds + a_w * 128 + pp * 16 + (l4 & 1) * 8) = pk;
        }
        LGKM_BARRIER;
        #pragma unroll
        for (int ks = 0; ks < 2; ++ks) {
            const int d = 16 * w + l15;
            bf16x8 vf = *(const bf16x8*)&vt_lds[buf][d * 64 + (((ks * 4 + l4) ^ (d & 7)) * 8)];
            #pragma unroll
            for (int mi = 0; mi < 4; ++mi) {
                const int a = 16 * mi + l15;
                bf16x8 pf = *(const bf16x8*)((char*)p_lds + a * 128 + (((ks * 4 + l4) ^ (a & 7)) * 16));
                acc_o[mi] = __builtin_amdgcn_mfma_f32_16x16x32_bf16(pf, vf, acc_o[mi], 0, 0, 0);
                acc_den[mi] = __builtin_amdgcn_mfma_f32_16x16x32_bf16(onef, pf, acc_den[mi], 0, 0, 0);
            }
        }
    }
    const size_t pbase = (size_t)bh * 7 + ns;
    if (w == 0 && lane < 16) {
        #pragma unroll
        for (int mi = 0; mi < 4; ++mi)
            ps[pbase * 64 + 16 * mi + lane] = acc_den[mi][0];
    }
    #pragma unroll
    for (int mi = 0; mi < 4; ++mi)
        *(f32x4*)&pav_t[(pbase * 64 + 16 * w + l15) * 64 + 16 * mi + l4 * 4] = acc_o[mi];
}

// ---------------------------------------------------------------------------
// Q-side attention with INLINED combine: each block first reduces its bh's
// 7 partials (ps, pav_t) into av_lds (bf16 [d][a]), then runs 7 n-tiles.
// ---------------------------------------------------------------------------
__global__ __launch_bounds__(256) void q_attn_kernel(
    const u16* __restrict__ at_bf, const u16* __restrict__ qk,
    const float* __restrict__ ps, const float* __restrict__ pav_t,
    u16* __restrict__ attn_out) {
    __shared__ u16 q_lds[2][64 * 64];
    __shared__ u16 p_lds[64 * 64];
    __shared__ u16 av_lds[64 * 64];   // [d][a]
    __shared__ float sinv[64];
    const int grp = blockIdx.x;
    const int bh = blockIdx.y;
    const int b = bh / 12, h = bh - b * 12;
    const int t = threadIdx.x, lane = t & 63, w = t >> 6;
    const int l15 = lane & 15, l4 = lane >> 4;

    auto STAGE_Q = [&](int buf, int nt) {
        const int n0 = nt * 64;
        #pragma unroll
        for (int p = 0; p < 2; ++p) {
            const int row = p * 32 + w * 8 + (lane >> 3);
            const int sc = ((lane & 7) ^ (row & 7)) * 8;
            gload_lds16(qk + ((size_t)(b * 3136 + n0 + row)) * 1536 + h * 64 + sc,
                        &q_lds[buf][(p * 32 + w * 8) * 64]);
        }
    };
    STAGE_Q(0, grp * 7);

    // ---- inline combine: av_lds[d][a] = (sum_ns pav_t) * sinv[a] ----
    if (t < 64) {
        float s = 0.f;
        #pragma unroll
        for (int ns = 0; ns < 7; ++ns) s += ps[((size_t)bh * 7 + ns) * 64 + t];
        sinv[t] = 1.0f / s;
    }
    __syncthreads();
    {
        const int d = t >> 2, aseg = t & 3;
        f32x4 acc[4];
        #pragma unroll
        for (int g = 0; g < 4; ++g) acc[g] = (f32x4){0.f, 0.f, 0.f, 0.f};
        #pragma unroll
        for (int ns = 0; ns < 7; ++ns) {
            const float* src = pav_t + (((size_t)bh * 7 + ns) * 64 + d) * 64 + aseg * 16;
            #pragma unroll
            for (int g = 0; g < 4; ++g) acc[g] += *(const f32x4*)&src[g * 4];
        }
        u16x8 o0, o1;
        #pragma unroll
        for (int g = 0; g < 4; ++g)
            #pragma unroll
            for (int jj = 0; jj < 4; ++jj) {
                const u16 v = f2b(acc[g][jj] * sinv[aseg * 16 + g * 4 + jj]);
                if (g < 2) o0[g * 4 + jj] = v; else o1[(g - 2) * 4 + jj] = v;
            }
        *(u16x8*)&av_lds[d * 64 + aseg * 16] = o0;
        *(u16x8*)&av_lds[d * 64 + aseg * 16 + 8] = o1;
    }
    __syncthreads();

    bf16x8 atf[4][2], avf[4][2];
    #pragma unroll
    for (int mi = 0; mi < 4; ++mi)
        #pragma unroll
        for (int ks = 0; ks < 2; ++ks) {
            atf[mi][ks] = *(const bf16x8*)&at_bf[((size_t)b * 64 + 16 * mi + l15) * 768 + h * 64 + ks * 32 + l4 * 8];
            avf[mi][ks] = *(const bf16x8*)&av_lds[(16 * mi + l15) * 64 + ks * 32 + l4 * 8];
        }
    const bf16x8 onef = ones_frag();

    const int nn = 16 * w + l15;
    for (int i = 0; i < 7; ++i) {
        const int buf = i & 1;
        const int nt = grp * 7 + i;
        __syncthreads();
        if (i < 6) STAGE_Q(buf ^ 1, nt + 1);
        f32x4 acc_l[4];
        #pragma unroll
        for (int mi = 0; mi < 4; ++mi) acc_l[mi] = (f32x4){0.f, 0.f, 0.f, 0.f};
        #pragma unroll
        for (int ks = 0; ks < 2; ++ks) {
            bf16x8 qf = *(const bf16x8*)&q_lds[buf][nn * 64 + (((ks * 4 + l4) ^ (nn & 7)) * 8)];
            #pragma unroll
            for (int mi = 0; mi < 4; ++mi)
                acc_l[mi] = __builtin_amdgcn_mfma_f32_16x16x32_bf16(atf[mi][ks], qf, acc_l[mi], 0, 0, 0);
        }
        #pragma unroll
        for (int mi = 0; mi < 4; ++mi) {
            u16x4 pk;
            #pragma unroll
            for (int rr = 0; rr < 4; ++rr) {
                const int a = 16 * mi + l4 * 4 + rr;
                pk[rr] = (a < 49) ? f2b(__expf(acc_l[mi][rr])) : (u16)0;
            }
            const int pp = (2 * mi + (l4 >> 1)) ^ (nn & 7);
            *(u16x4*)((char*)p_lds + nn * 128 + pp * 16 + (l4 & 1) * 8) = pk;
        }
        LGKM_BARRIER;
        f32x4 acc_o[4], den;
        #pragma unroll
        for (int mi = 0; mi < 4; ++mi) acc_o[mi] = (f32x4){0.f, 0.f, 0.f, 0.f};
        den = (f32x4){0.f, 0.f, 0.f, 0.f};
        #pragma unroll
        for (int ks = 0; ks < 2; ++ks) {
            bf16x8 pf = *(const bf16x8*)((char*)p_lds + nn * 128 + (((ks * 4 + l4) ^ (nn & 7)) * 16));
            den = __builtin_amdgcn_mfma_f32_16x16x32_bf16(onef, pf, den, 0, 0, 0);
            #pragma unroll
            for (int mi = 0; mi < 4; ++mi)
                acc_o[mi] = __builtin_amdgcn_mfma_f32_16x16x32_bf16(avf[mi][ks], pf, acc_o[mi], 0, 0, 0);
        }
        const float rinv = 1.0f / den[0];
        const size_t obase = ((size_t)(b * 3136 + nt * 64 + nn)) * 768 + h * 64;
        #pragma unroll
        for (int mi = 0; mi < 4; ++mi) {
            u16x4 ov;
            #pragma unroll
            for (int rr = 0; rr < 4; ++rr) ov[rr] = f2b(acc_o[mi][rr] * rinv);
            *(u16x4*)&attn_out[obase + 16 * mi + l4 * 4] = ov;
        }
    }
}

// ---------------------------------------------------------------------------
extern "C" void kernel_launch(void* const* d_in, const int* in_sizes, int n_in,
                              void* d_out, int out_size, void* d_ws, size_t ws_size,
                              hipStream_t stream) {
    (void)in_sizes; (void)n_in; (void)out_size; (void)ws_size;
    const float* x     = (const float*)d_in[0];
    const float* y     = (const float*)d_in[1];
    const float* ln1w  = (const float*)d_in[2];
    const float* ln1b  = (const float*)d_in[3];
    const float* ln2w  = (const float*)d_in[4];
    const float* ln2b  = (const float*)d_in[5];
    const float* wq1   = (const float*)d_in[6];
    const float* wq2   = (const float*)d_in[7];
    const float* wkv   = (const float*)d_in[8];
    const float* wproj = (const float*)d_in[9];
    const float* bproj = (const float*)d_in[10];
    float* out = (float*)d_out;

    char* ws = (char*)d_ws;
    // Regions. Aliasing plan:
    //   xn region: xn (written B, read C) -> pav_t (written D, read E)
    //   vT region: vT (written C, read D) -> attn_out (written E, read F)
    u16*   xn     = (u16*)(ws);                    // 38,535,168
    u16*   qk     = (u16*)(ws + 38535168);         // 77,070,336 ([n][1536])
    u16*   vT     = (u16*)(ws + 115605504);        // 38,535,168 ([b*768+c][n])
    u16*   wcat   = (u16*)(ws + 154140672);        // 3,538,944
    u16*   wq2b   = (u16*)(ws + 157679616);        // 1,179,648
    u16*   wpb    = (u16*)(ws + 158859264);        // 1,179,648
    u16*   at_a   = (u16*)(ws + 160038912);        // 786,432
    u16*   at_bf  = (u16*)(ws + 160825344);        // 786,432
    float* ps     = (float*)(ws + 161611776);      // 172,032
    float* rsb    = (float*)(ws + 161783808);      // 100,352
    float* mrsb   = (float*)(ws + 161884160);      // 100,352
    float* xmu    = (float*)(ws + 161984512);      // 100,352
    float* xrs    = (float*)(ws + 162084864);      // 100,352 (end 162,185,216)
    float* pav_t  = (float*)(ws);                  // in xn region
    u16*   attn_out = vT;                          // in vT region

    pack_stats_kernel<<<dim3(3088), dim3(256), 0, stream>>>(
        wq1, wq2, wkv, wproj, wcat, wq2b, wpb, at_a, x, y, xmu, xrs, rsb, mrsb);
    norm_pool_kernel<<<dim3(1456), dim3(256), 0, stream>>>(
        x, ln1w, ln1b, xmu, xrs, xn, y, ln2w, ln2b, rsb, mrsb, at_a);
    gemm_qkv_at_kernel<<<dim3(3552), dim3(256), 0, stream>>>(
        xn, wcat, qk, vT, at_a, wq2b, at_bf);
    agent_attn_kernel<<<dim3(7, 96), dim3(256), 0, stream>>>(at_bf, qk, vT, ps, pav_t);
    q_attn_kernel<<<dim3(7, 96), dim3(256), 0, stream>>>(at_bf, qk, ps, pav_t, attn_out);
    gemm_proj_kernel<<<dim3(1176), dim3(256), 0, stream>>>(attn_out, wpb, out, bproj);
}

// Round 13
// 302.189 us; speedup vs baseline: 1.0710x; 1.0070x over previous
//
#include <hip/hip_runtime.h>

typedef unsigned short u16;
typedef u16 u16x4 __attribute__((ext_vector_type(4)));
typedef u16 u16x8 __attribute__((ext_vector_type(8)));
typedef __bf16 bf16x8 __attribute__((ext_vector_type(8)));
typedef float f32x4 __attribute__((ext_vector_type(4)));

__device__ __forceinline__ float b2f(u16 u) {
    union { unsigned int i; float f; } v; v.i = ((unsigned int)u) << 16; return v.f;
}
__device__ __forceinline__ u16 f2b(float f) {
    union { float f; unsigned int i; } v; v.f = f;
    unsigned int r = v.i + 0x7fffu + ((v.i >> 16) & 1u);
    return (u16)(r >> 16);
}
__device__ __forceinline__ void gload_lds16(const u16* g, u16* l) {
    __builtin_amdgcn_global_load_lds(
        (const __attribute__((address_space(1))) void*)g,
        (__attribute__((address_space(3))) void*)l, 16, 0, 0);
}
__device__ __forceinline__ bf16x8 ones_frag() {
    union { u16x8 u; bf16x8 b; } v;
    #pragma unroll
    for (int i = 0; i < 8; ++i) v.u[i] = 0x3F80;
    return v.b;
}
#define LGKM_BARRIER do { \
    asm volatile("s_waitcnt lgkmcnt(0)" ::: "memory"); \
    __builtin_amdgcn_s_barrier(); \
    __builtin_amdgcn_sched_barrier(0); } while (0)

// ---------------------------------------------------------------------------
// Fused launch A: blocks 0..2303 pack weights; 2304..3087 per-position LN
// stats for x (xmu,xrs) and y (rs, mu*rs).
// ---------------------------------------------------------------------------
__global__ __launch_bounds__(256) void pack_stats_kernel(
    const float* __restrict__ wq1, const float* __restrict__ wq2,
    const float* __restrict__ wkv, const float* __restrict__ wproj,
    u16* __restrict__ wcat, u16* __restrict__ wq2b, u16* __restrict__ wpb,
    u16* __restrict__ at_a,
    const float* __restrict__ x, const float* __restrict__ y,
    float* __restrict__ xmu, float* __restrict__ xrs,
    float* __restrict__ rsb, float* __restrict__ mrsb) {
    __shared__ float red[16][64];
    __shared__ float red2[16][64];
    const int bxg = blockIdx.x;
    const int t = threadIdx.x;
    if (bxg < 2304) {
        const int e = bxg * 256 + t;
        const float scale = 0.125f;
        wcat[e]           = f2b(wq1[e] * scale);
        wcat[589824 + e]  = f2b(wkv[e] * scale);
        wcat[1179648 + e] = f2b(wkv[589824 + e]);
        wq2b[e]           = f2b(wq2[e]);
        wpb[e]            = f2b(wproj[e]);
        if (e < 92160) {   // zero at_a pad rows 49..63 per batch
            int bb = e / 11520, rem = e - bb * 11520;
            at_a[(size_t)bb * 49152 + 37632 + rem] = 0;
        }
        return;
    }
    const int bx0 = bxg - 2304;
    const int isY = bx0 >= 392;
    const int bx = isY ? bx0 - 392 : bx0;
    const int b = bx / 49, tile = bx - b * 49;
    const int pos0 = tile * 64;
    const int pq = t & 15, q = t >> 4;
    const float* src = (isY ? y : x) + (size_t)b * 2408448 + pos0;
    f32x4 s = {0.f, 0.f, 0.f, 0.f}, s2 = {0.f, 0.f, 0.f, 0.f};
    #pragma unroll 8
    for (int c = q; c < 768; c += 16) {
        f32x4 v = *(const f32x4*)&src[(size_t)c * 3136 + pq * 4];
        s += v; s2 += v * v;
    }
    *(f32x4*)&red[q][pq * 4] = s;
    *(f32x4*)&red2[q][pq * 4] = s2;
    __syncthreads();
    if (t < 64) {
        float ss = 0.f, qq = 0.f;
        #pragma unroll
        for (int r = 0; r < 16; ++r) { ss += red[r][t]; qq += red2[r][t]; }
        float mu = ss * (1.0f / 768.0f);
        float var = qq * (1.0f / 768.0f) - mu * mu;
        float rv = rsqrtf(var + 1e-5f);
        const size_t o = (size_t)b * 3136 + pos0 + t;
        if (isY) { rsb[o] = rv; mrsb[o] = mu * rv; }
        else     { xmu[o] = mu; xrs[o] = rv; }
    }
}

// ---------------------------------------------------------------------------
// Fused launch B: blocks 0..783 = xnorm (LN+transpose x -> xn bf16);
// blocks 784..1455 = y_pool (pooled LN(y) -> at_a bf16).
// ---------------------------------------------------------------------------
__global__ __launch_bounds__(256) void norm_pool_kernel(
    const float* __restrict__ x, const float* __restrict__ lw1,
    const float* __restrict__ lb1, const float* __restrict__ xmu,
    const float* __restrict__ xrs, u16* __restrict__ xn,
    const float* __restrict__ y, const float* __restrict__ lw2,
    const float* __restrict__ lb2, const float* __restrict__ rsb,
    const float* __restrict__ mrsb, u16* __restrict__ at_a) {
    __shared__ u16 tl[128][68];
    const int bxg = blockIdx.x;
    const int t = threadIdx.x;
    if (bxg < 784) {
        const int half = bxg / 392;
        const int bx = bxg - half * 392;
        const int b = bx / 49, tile = bx - b * 49;
        const int pos0 = tile * 64;
        const int pq = t & 15, q = t >> 4;
        const int p = t >> 2, sub = t & 3;
        const float* xb = x + (size_t)b * 2408448 + pos0;
        const float mu = xmu[(size_t)b * 3136 + pos0 + p];
        const float rs = xrs[(size_t)b * 3136 + pos0 + p];
        const size_t orow = ((size_t)(b * 3136 + pos0 + p)) * 768;
        for (int ci = 0; ci < 3; ++ci) {
            const int c0 = half * 384 + ci * 128;
            #pragma unroll
            for (int s8 = 0; s8 < 8; ++s8) {
                const int cr = s8 * 16 + q;
                f32x4 v = *(const f32x4*)&xb[(size_t)(c0 + cr) * 3136 + pq * 4];
                u16x4 pk;
                pk[0] = f2b(v[0]); pk[1] = f2b(v[1]); pk[2] = f2b(v[2]); pk[3] = f2b(v[3]);
                *(u16x4*)&tl[cr][pq * 4] = pk;
            }
            __syncthreads();
            #pragma unroll
            for (int k = 0; k < 4; ++k) {
                const int cb = k * 32 + sub * 8;
                f32x4 w0 = *(const f32x4*)&lw1[c0 + cb];
                f32x4 w1 = *(const f32x4*)&lw1[c0 + cb + 4];
                f32x4 b0 = *(const f32x4*)&lb1[c0 + cb];
                f32x4 b1 = *(const f32x4*)&lb1[c0 + cb + 4];
                u16x8 o;
                #pragma unroll
                for (int j = 0; j < 4; ++j) {
                    float v = b2f(tl[cb + j][p]);
                    o[j] = f2b((v - mu) * rs * w0[j] + b0[j]);
                }
                #pragma unroll
                for (int j = 0; j < 4; ++j) {
                    float v = b2f(tl[cb + 4 + j][p]);
                    o[4 + j] = f2b((v - mu) * rs * w1[j] + b1[j]);
                }
                *(u16x8*)&xn[orow + c0 + cb] = o;
            }
            __syncthreads();
        }
        return;
    }
    // ---- y_pool half ----
    const int j = bxg - 784;
    const int cgrp = j % 12;
    const int bpi = j / 12;
    const int b = bpi / 7, pi = bpi - b * 7;
    const int lane = t & 63, w = t >> 6;
    const int pbase = b * 3136 + pi * 448;
    const int p0 = (lane >> 3) * 56 + (lane & 7);
    float rsv[7], s3f[7];
    #pragma unroll
    for (int it = 0; it < 7; ++it) {
        rsv[it] = rsb[pbase + p0 + it * 8];
        float m = mrsb[pbase + p0 + it * 8];
        #pragma unroll
        for (int msk = 1; msk < 64; msk <<= 1) m += __shfl_xor(m, msk, 64);
        s3f[it] = m;
    }
    const float* yb = y + (size_t)b * 2408448 + pi * 448 + p0;
    u16* yo = at_a + ((size_t)b * 64 + pi * 7) * 768;
    for (int ci = 0; ci < 16; ++ci) {
        const int c = cgrp * 64 + w * 16 + ci;
        const float* yc = yb + (size_t)c * 3136;
        float v[7];
        #pragma unroll
        for (int it = 0; it < 7; ++it) v[it] = yc[it * 8] * rsv[it];
        #pragma unroll
        for (int it = 0; it < 7; ++it) {
            float s = v[it];
            #pragma unroll
            for (int msk = 1; msk < 64; msk <<= 1) s += __shfl_xor(s, msk, 64);
            v[it] = s;
        }
        if (lane == 0) {
            const float wv = lw2[c], bv = lb2[c];
            #pragma unroll
            for (int it = 0; it < 7; ++it)
                yo[(size_t)it * 768 + c] = f2b(wv * (v[it] - s3f[it]) * (1.0f / 64.0f) + bv);
        }
    }
}

// ---------------------------------------------------------------------------
// 128x128 4-wave m97-structure GEMM body (proven: 114 us qkv, ~772 TF).
// Two-sided LDS slot swizzle; caller supplies (rt, ct).
// MODE 0 (qkv): cols <1536 -> qk[n][1536]; cols >=1536 -> vT[(b*768+c)][n].
// MODE 1 (proj): f32 +bias, transposed (b,o,n). MODE 2: plain bf16 [M][768].
// ---------------------------------------------------------------------------
template<int MODE>
__device__ __forceinline__ void gemm_body(
    int rt, int ct, const u16* __restrict__ A, const u16* __restrict__ B,
    u16* __restrict__ qk, u16* __restrict__ vT,
    float* __restrict__ Cf, const float* __restrict__ bias,
    u16* As, u16* Bs) {
    const int t = threadIdx.x;
    const int lane = t & 63;
    const int w = t >> 6;
    const int wr = w >> 1, wc = w & 1;
    const int l15 = lane & 15, l4 = lane >> 4;

    const u16* Ab = A + (size_t)rt * 128 * 768;
    const u16* Bb = B + (size_t)ct * 128 * 768;
    const int grh = lane >> 3;
    const int gsl = (lane & 7) ^ grh;

    f32x4 acc[4][4];
    #pragma unroll
    for (int mi = 0; mi < 4; ++mi)
        #pragma unroll
        for (int ni = 0; ni < 4; ++ni)
            acc[mi][ni] = (f32x4){0.f, 0.f, 0.f, 0.f};

    for (int kt = 0; kt < 12; ++kt) {
        if (kt) __syncthreads();
        #pragma unroll
        for (int i = 0; i < 4; ++i) {
            const int chunk = w * 4 + i;
            const int row = chunk * 8 + grh;
            gload_lds16(Ab + (size_t)row * 768 + kt * 64 + gsl * 8, &As[chunk * 512]);
            gload_lds16(Bb + (size_t)row * 768 + kt * 64 + gsl * 8, &Bs[chunk * 512]);
        }
        __syncthreads();
        #pragma unroll
        for (int ks = 0; ks < 2; ++ks) {
            bf16x8 af[4], bfv[4];
            #pragma unroll
            for (int mi = 0; mi < 4; ++mi) {
                const int row = wr * 64 + mi * 16 + l15;
                af[mi] = *(const bf16x8*)&As[row * 64 + (((ks * 4 + l4) ^ (row & 7)) * 8)];
            }
            #pragma unroll
            for (int ni = 0; ni < 4; ++ni) {
                const int row = wc * 64 + ni * 16 + l15;
                bfv[ni] = *(const bf16x8*)&Bs[row * 64 + (((ks * 4 + l4) ^ (row & 7)) * 8)];
            }
            #pragma unroll
            for (int mi = 0; mi < 4; ++mi)
                #pragma unroll
                for (int ni = 0; ni < 4; ++ni)
                    acc[mi][ni] = __builtin_amdgcn_mfma_f32_16x16x32_bf16(
                        af[mi], bfv[ni], acc[mi][ni], 0, 0, 0);
        }
    }

    if constexpr (MODE == 0) {
        #pragma unroll
        for (int mi = 0; mi < 4; ++mi)
            #pragma unroll
            for (int ni = 0; ni < 4; ++ni) {
                const int row0 = rt * 128 + wr * 64 + mi * 16 + l4 * 4;
                const int col = ct * 128 + wc * 64 + ni * 16 + l15;
                if (col < 1536) {
                    #pragma unroll
                    for (int rr = 0; rr < 4; ++rr)
                        qk[(size_t)(row0 + rr) * 1536 + col] = f2b(acc[mi][ni][rr]);
                } else {
                    const int c = col - 1536;
                    const int bb = row0 / 3136;
                    const int nn2 = row0 - bb * 3136;
                    u16x4 pk;
                    #pragma unroll
                    for (int rr = 0; rr < 4; ++rr) pk[rr] = f2b(acc[mi][ni][rr]);
                    *(u16x4*)&vT[((size_t)(bb * 768 + c)) * 3136 + nn2] = pk;
                }
            }
    } else if constexpr (MODE == 1) {
        #pragma unroll
        for (int ni = 0; ni < 4; ++ni) {
            const int col = ct * 128 + wc * 64 + ni * 16 + l15;
            const float bv = bias[col];
            #pragma unroll
            for (int mi = 0; mi < 4; ++mi) {
                const int grow = rt * 128 + wr * 64 + mi * 16 + l4 * 4;
                const int bb = grow / 3136;
                const int nn2 = grow - bb * 3136;
                f32x4 vv = acc[mi][ni];
                vv[0] += bv; vv[1] += bv; vv[2] += bv; vv[3] += bv;
                *(f32x4*)(Cf + (size_t)bb * 2408448 + (size_t)col * 3136 + nn2) = vv;
            }
        }
    } else {
        #pragma unroll
        for (int mi = 0; mi < 4; ++mi)
            #pragma unroll
            for (int ni = 0; ni < 4; ++ni) {
                const int row0 = rt * 128 + wr * 64 + mi * 16 + l4 * 4;
                const int col = ct * 128 + wc * 64 + ni * 16 + l15;
                #pragma unroll
                for (int rr = 0; rr < 4; ++rr)
                    qk[(size_t)(row0 + rr) * 768 + col] = f2b(acc[mi][ni][rr]);
            }
    }
}

// Bijective XCD swizzle + GROUP_RT=4 tile order. Requires NRT % 4 == 0.
__device__ __forceinline__ void map_tile(int orig, int nwg, int NCT,
                                         int& rt, int& ct) {
    const int xcd = orig & 7;
    const int qd = nwg >> 3, r = nwg & 7;
    const int wg = (xcd < r ? xcd * (qd + 1) : r * (qd + 1) + (xcd - r) * qd) + (orig >> 3);
    const int grp = NCT * 4;
    const int rtg = wg / grp, rem = wg % grp;
    ct = rem >> 2;
    rt = rtg * 4 + (rem & 3);
}

// Fused launch C: blocks 0..3527 = qkv GEMM; 3528..3551 = agent-token GEMM.
__global__ __launch_bounds__(256) void gemm_qkv_at_kernel(
    const u16* __restrict__ xn, const u16* __restrict__ wcat,
    u16* __restrict__ qk, u16* __restrict__ vT,
    const u16* __restrict__ at_a, const u16* __restrict__ wq2b,
    u16* __restrict__ at_bf) {
    __shared__ u16 As[128 * 64];
    __shared__ u16 Bs[128 * 64];
    const int bx = blockIdx.x;
    if (bx < 3528) {
        int rt, ct;
        map_tile(bx, 3528, 18, rt, ct);
        gemm_body<0>(rt, ct, xn, wcat, qk, vT, nullptr, nullptr, As, Bs);
    } else {
        const int wg = bx - 3528;            // 24 blocks: NRT=4, NCT=6
        gemm_body<2>(wg / 6, wg % 6, at_a, wq2b, at_bf, nullptr, nullptr, nullptr, As, Bs);
    }
}

__global__ __launch_bounds__(256) void gemm_proj_kernel(
    const u16* __restrict__ attn_out, const u16* __restrict__ wpb,
    float* __restrict__ out, const float* __restrict__ bproj) {
    __shared__ u16 As[128 * 64];
    __shared__ u16 Bs[128 * 64];
    int rt, ct;
    map_tile(blockIdx.x, 1176, 6, rt, ct);
    gemm_body<1>(rt, ct, attn_out, wpb, nullptr, nullptr, out, bproj, As, Bs);
}

// ---------------------------------------------------------------------------
// Agent-side attention (MFMA), n-split x7 partials per (b,h). LDS-staged K/V
// (staging IS the coalescing transform — R11 direct-L2 reads regressed 20us:
// per-fragment global reads are 16-way uncoalesced gathers).
// ---------------------------------------------------------------------------
__global__ __launch_bounds__(256) void agent_attn_kernel(
    const u16* __restrict__ at_bf, const u16* __restrict__ qk,
    const u16* __restrict__ vT, float* __restrict__ ps,
    float* __restrict__ pav_t) {
    __shared__ u16 k_lds[2][64 * 64];
    __shared__ u16 vt_lds[2][64 * 64];
    __shared__ u16 p_lds[64 * 64];
    const int ns = blockIdx.x;
    const int bh = blockIdx.y;
    const int b = bh / 12, h = bh - b * 12;
    const int t = threadIdx.x, lane = t & 63, w = t >> 6;
    const int l15 = lane & 15, l4 = lane >> 4;

    bf16x8 atf[2];
    #pragma unroll
    for (int ks = 0; ks < 2; ++ks)
        atf[ks] = *(const bf16x8*)&at_bf[((size_t)b * 64 + 16 * w + l15) * 768 + h * 64 + ks * 32 + l4 * 8];
    const bf16x8 onef = ones_frag();

    f32x4 acc_o[4], acc_den[4];
    #pragma unroll
    for (int mi = 0; mi < 4; ++mi) {
        acc_o[mi] = (f32x4){0.f, 0.f, 0.f, 0.f};
        acc_den[mi] = (f32x4){0.f, 0.f, 0.f, 0.f};
    }

    auto STAGE = [&](int buf, int tile) {
        const int n0 = ns * 448 + tile * 64;
        #pragma unroll
        for (int p = 0; p < 2; ++p) {
            const int row = p * 32 + w * 8 + (lane >> 3);
            const int sc = ((lane & 7) ^ (row & 7)) * 8;
            gload_lds16(qk + ((size_t)(b * 3136 + n0 + row)) * 1536 + 768 + h * 64 + sc,
                        &k_lds[buf][(p * 32 + w * 8) * 64]);
            gload_lds16(vT + ((size_t)(bh * 64 + row)) * 3136 + n0 + sc,
                        &vt_lds[buf][(p * 32 + w * 8) * 64]);
        }
    };

    STAGE(0, 0);
    for (int tile = 0; tile < 7; ++tile) {
        const int buf = tile & 1;
        __syncthreads();
        if (tile < 6) STAGE(buf ^ 1, tile + 1);
        f32x4 acc_s[4];
        #pragma unroll
        for (int mi = 0; mi < 4; ++mi) acc_s[mi] = (f32x4){0.f, 0.f, 0.f, 0.f};
        #pragma unroll
        for (int ks = 0; ks < 2; ++ks)
            #pragma unroll
            for (int mi = 0; mi < 4; ++mi) {
                const int row = 16 * mi + l15;
                bf16x8 kf = *(const bf16x8*)&k_lds[buf][row * 64 + (((ks * 4 + l4) ^ (row & 7)) * 8)];
                acc_s[mi] = __builtin_amdgcn_mfma_f32_16x16x32_bf16(kf, atf[ks], acc_s[mi], 0, 0, 0);
            }
        const int a_w = 16 * w + l15;
        #pragma unroll
        for (int mi = 0; mi < 4; ++mi) {
            u16x4 pk;
            #pragma unroll
            for (int rr = 0; rr < 4; ++rr) pk[rr] = f2b(__expf(acc_s[mi][rr]));
            const int pp = (2 * mi + (l4 >> 1)) ^ (a_w & 7);
            *(u16x4*)((char*)p_lds + a_w * 128 + pp * 16 + (l4 & 1) * 8) = pk;
        }
        LGKM_BARRIER;
        #pragma unroll
        for (int ks = 0; ks < 2; ++ks) {
            const int d = 16 * w + l15;
            bf16x8 vf = *(const bf16x8*)&vt_lds[buf][d * 64 + (((ks * 4 + l4) ^ (d & 7)) * 8)];
            #pragma unroll
            for (int mi = 0; mi < 4; ++mi) {
                const int a = 16 * mi + l15;
                bf16x8 pf = *(const bf16x8*)((char*)p_lds + a * 128 + (((ks * 4 + l4) ^ (a & 7)) * 16));
                acc_o[mi] = __builtin_amdgcn_mfma_f32_16x16x32_bf16(pf, vf, acc_o[mi], 0, 0, 0);
                acc_den[mi] = __builtin_amdgcn_mfma_f32_16x16x32_bf16(onef, pf, acc_den[mi], 0, 0, 0);
            }
        }
    }
    const size_t pbase = (size_t)bh * 7 + ns;
    if (w == 0 && lane < 16) {
        #pragma unroll
        for (int mi = 0; mi < 4; ++mi)
            ps[pbase * 64 + 16 * mi + lane] = acc_den[mi][0];
    }
    #pragma unroll
    for (int mi = 0; mi < 4; ++mi)
        *(f32x4*)&pav_t[(pbase * 64 + 16 * w + l15) * 64 + 16 * mi + l4 * 4] = acc_o[mi];
}

// ---------------------------------------------------------------------------
// Q-side attention with INLINED combine: each block first reduces its bh's
// 7 partials (ps, pav_t) into av_lds (bf16 [d][a]), then runs 7 n-tiles.
// ---------------------------------------------------------------------------
__global__ __launch_bounds__(256) void q_attn_kernel(
    const u16* __restrict__ at_bf, const u16* __restrict__ qk,
    const float* __restrict__ ps, const float* __restrict__ pav_t,
    u16* __restrict__ attn_out) {
    __shared__ u16 q_lds[2][64 * 64];
    __shared__ u16 p_lds[64 * 64];
    __shared__ u16 av_lds[64 * 64];   // [d][a]
    __shared__ float sinv[64];
    const int grp = blockIdx.x;
    const int bh = blockIdx.y;
    const int b = bh / 12, h = bh - b * 12;
    const int t = threadIdx.x, lane = t & 63, w = t >> 6;
    const int l15 = lane & 15, l4 = lane >> 4;

    auto STAGE_Q = [&](int buf, int nt) {
        const int n0 = nt * 64;
        #pragma unroll
        for (int p = 0; p < 2; ++p) {
            const int row = p * 32 + w * 8 + (lane >> 3);
            const int sc = ((lane & 7) ^ (row & 7)) * 8;
            gload_lds16(qk + ((size_t)(b * 3136 + n0 + row)) * 1536 + h * 64 + sc,
                        &q_lds[buf][(p * 32 + w * 8) * 64]);
        }
    };
    STAGE_Q(0, grp * 7);

    // ---- inline combine: av_lds[d][a] = (sum_ns pav_t) * sinv[a] ----
    if (t < 64) {
        float s = 0.f;
        #pragma unroll
        for (int ns = 0; ns < 7; ++ns) s += ps[((size_t)bh * 7 + ns) * 64 + t];
        sinv[t] = 1.0f / s;
    }
    __syncthreads();
    {
        const int d = t >> 2, aseg = t & 3;
        f32x4 acc[4];
        #pragma unroll
        for (int g = 0; g < 4; ++g) acc[g] = (f32x4){0.f, 0.f, 0.f, 0.f};
        #pragma unroll
        for (int ns = 0; ns < 7; ++ns) {
            const float* src = pav_t + (((size_t)bh * 7 + ns) * 64 + d) * 64 + aseg * 16;
            #pragma unroll
            for (int g = 0; g < 4; ++g) acc[g] += *(const f32x4*)&src[g * 4];
        }
        u16x8 o0, o1;
        #pragma unroll
        for (int g = 0; g < 4; ++g)
            #pragma unroll
            for (int jj = 0; jj < 4; ++jj) {
                const u16 v = f2b(acc[g][jj] * sinv[aseg * 16 + g * 4 + jj]);
                if (g < 2) o0[g * 4 + jj] = v; else o1[(g - 2) * 4 + jj] = v;
            }
        *(u16x8*)&av_lds[d * 64 + aseg * 16] = o0;
        *(u16x8*)&av_lds[d * 64 + aseg * 16 + 8] = o1;
    }
    __syncthreads();

    bf16x8 atf[4][2], avf[4][2];
    #pragma unroll
    for (int mi = 0; mi < 4; ++mi)
        #pragma unroll
        for (int ks = 0; ks < 2; ++ks) {
            atf[mi][ks] = *(const bf16x8*)&at_bf[((size_t)b * 64 + 16 * mi + l15) * 768 + h * 64 + ks * 32 + l4 * 8];
            avf[mi][ks] = *(const bf16x8*)&av_lds[(16 * mi + l15) * 64 + ks * 32 + l4 * 8];
        }
    const bf16x8 onef = ones_frag();

    const int nn = 16 * w + l15;
    for (int i = 0; i < 7; ++i) {
        const int buf = i & 1;
        const int nt = grp * 7 + i;
        __syncthreads();
        if (i < 6) STAGE_Q(buf ^ 1, nt + 1);
        f32x4 acc_l[4];
        #pragma unroll
        for (int mi = 0; mi < 4; ++mi) acc_l[mi] = (f32x4){0.f, 0.f, 0.f, 0.f};
        #pragma unroll
        for (int ks = 0; ks < 2; ++ks) {
            bf16x8 qf = *(const bf16x8*)&q_lds[buf][nn * 64 + (((ks * 4 + l4) ^ (nn & 7)) * 8)];
            #pragma unroll
            for (int mi = 0; mi < 4; ++mi)
                acc_l[mi] = __builtin_amdgcn_mfma_f32_16x16x32_bf16(atf[mi][ks], qf, acc_l[mi], 0, 0, 0);
        }
        #pragma unroll
        for (int mi = 0; mi < 4; ++mi) {
            u16x4 pk;
            #pragma unroll
            for (int rr = 0; rr < 4; ++rr) {
                const int a = 16 * mi + l4 * 4 + rr;
                pk[rr] = (a < 49) ? f2b(__expf(acc_l[mi][rr])) : (u16)0;
            }
            const int pp = (2 * mi + (l4 >> 1)) ^ (nn & 7);
            *(u16x4*)((char*)p_lds + nn * 128 + pp * 16 + (l4 & 1) * 8) = pk;
        }
        LGKM_BARRIER;
        f32x4 acc_o[4], den;
        #pragma unroll
        for (int mi = 0; mi < 4; ++mi) acc_o[mi] = (f32x4){0.f, 0.f, 0.f, 0.f};
        den = (f32x4){0.f, 0.f, 0.f, 0.f};
        #pragma unroll
        for (int ks = 0; ks < 2; ++ks) {
            bf16x8 pf = *(const bf16x8*)((char*)p_lds + nn * 128 + (((ks * 4 + l4) ^ (nn & 7)) * 16));
            den = __builtin_amdgcn_mfma_f32_16x16x32_bf16(onef, pf, den, 0, 0, 0);
            #pragma unroll
            for (int mi = 0; mi < 4; ++mi)
                acc_o[mi] = __builtin_amdgcn_mfma_f32_16x16x32_bf16(avf[mi][ks], pf, acc_o[mi], 0, 0, 0);
        }
        const float rinv = 1.0f / den[0];
        const size_t obase = ((size_t)(b * 3136 + nt * 64 + nn)) * 768 + h * 64;
        #pragma unroll
        for (int mi = 0; mi < 4; ++mi) {
            u16x4 ov;
            #pragma unroll
            for (int rr = 0; rr < 4; ++rr) ov[rr] = f2b(acc_o[mi][rr] * rinv);
            *(u16x4*)&attn_out[obase + 16 * mi + l4 * 4] = ov;
        }
    }
}

// ---------------------------------------------------------------------------
extern "C" void kernel_launch(void* const* d_in, const int* in_sizes, int n_in,
                              void* d_out, int out_size, void* d_ws, size_t ws_size,
                              hipStream_t stream) {
    (void)in_sizes; (void)n_in; (void)out_size; (void)ws_size;
    const float* x     = (const float*)d_in[0];
    const float* y     = (const float*)d_in[1];
    const float* ln1w  = (const float*)d_in[2];
    const float* ln1b  = (const float*)d_in[3];
    const float* ln2w  = (const float*)d_in[4];
    const float* ln2b  = (const float*)d_in[5];
    const float* wq1   = (const float*)d_in[6];
    const float* wq2   = (const float*)d_in[7];
    const float* wkv   = (const float*)d_in[8];
    const float* wproj = (const float*)d_in[9];
    const float* bproj = (const float*)d_in[10];
    float* out = (float*)d_out;

    char* ws = (char*)d_ws;
    // Regions. Aliasing plan:
    //   xn region: xn (written B, read C) -> pav_t (written D, read E)
    //   vT region: vT (written C, read D) -> attn_out (written E, read F)
    u16*   xn     = (u16*)(ws);                    // 38,535,168
    u16*   qk     = (u16*)(ws + 38535168);         // 77,070,336 ([n][1536])
    u16*   vT     = (u16*)(ws + 115605504);        // 38,535,168 ([b*768+c][n])
    u16*   wcat   = (u16*)(ws + 154140672);        // 3,538,944
    u16*   wq2b   = (u16*)(ws + 157679616);        // 1,179,648
    u16*   wpb    = (u16*)(ws + 158859264);        // 1,179,648
    u16*   at_a   = (u16*)(ws + 160038912);        // 786,432
    u16*   at_bf  = (u16*)(ws + 160825344);        // 786,432
    float* ps     = (float*)(ws + 161611776);      // 172,032
    float* rsb    = (float*)(ws + 161783808);      // 100,352
    float* mrsb   = (float*)(ws + 161884160);      // 100,352
    float* xmu    = (float*)(ws + 161984512);      // 100,352
    float* xrs    = (float*)(ws + 162084864);      // 100,352 (end 162,185,216)
    float* pav_t  = (float*)(ws);                  // in xn region
    u16*   attn_out = vT;                          // in vT region

    pack_stats_kernel<<<dim3(3088), dim3(256), 0, stream>>>(
        wq1, wq2, wkv, wproj, wcat, wq2b, wpb, at_a, x, y, xmu, xrs, rsb, mrsb);
    norm_pool_kernel<<<dim3(1456), dim3(256), 0, stream>>>(
        x, ln1w, ln1b, xmu, xrs, xn, y, ln2w, ln2b, rsb, mrsb, at_a);
    gemm_qkv_at_kernel<<<dim3(3552), dim3(256), 0, stream>>>(
        xn, wcat, qk, vT, at_a, wq2b, at_bf);
    agent_attn_kernel<<<dim3(7, 96), dim3(256), 0, stream>>>(at_bf, qk, vT, ps, pav_t);
    q_attn_kernel<<<dim3(7, 96), dim3(256), 0, stream>>>(at_bf, qk, ps, pav_t, attn_out);
    gemm_proj_kernel<<<dim3(1176), dim3(256), 0, stream>>>(attn_out, wpb, out, bproj);
}